// Round 3
// baseline (481.427 us; speedup 1.0000x reference)
//
#include <hip/hip_runtime.h>
#include <hip/hip_cooperative_groups.h>

namespace cg = cooperative_groups;

#define B_SZ  2
#define N_PTS 16384
#define M_CTR 4096
#define C_FT  32
#define K_NB  32
#define NCH   35   // 3 + C_FT
#define CH_STRIDE (K_NB * M_CTR)   // 131072
#define CELLS 10
#define NCELL (CELLS * CELLS * CELLS)

typedef float vfloat2 __attribute__((ext_vector_type(2)));  // NT-store-able

// ---------------------------------------------------------------------------
// Exact single-rounded f32 ops, opaque to the compiler. v_fma_f32 ONLY where
// the numpy golden fuses (einsum cp accumulation). absmax==0.0 since R6 —
// DO NOT change the math.
// ---------------------------------------------------------------------------
__device__ __forceinline__ float fmul(float a, float b) {
    float r; asm("v_mul_f32 %0, %1, %2" : "=v"(r) : "v"(a), "v"(b)); return r;
}
__device__ __forceinline__ float fadd(float a, float b) {
    float r; asm("v_add_f32 %0, %1, %2" : "=v"(r) : "v"(a), "v"(b)); return r;
}
__device__ __forceinline__ float fsub(float a, float b) {
    float r; asm("v_sub_f32 %0, %1, %2" : "=v"(r) : "v"(a), "v"(b)); return r;
}
__device__ __forceinline__ float ffma(float a, float b, float c) {
    float r; asm("v_fma_f32 %0, %1, %2, %3" : "=v"(r) : "v"(a), "v"(b), "v"(c));
    return r;
}

__device__ __forceinline__ bool bq_valid(float x, float y, float z,
                                         float cx, float cy, float cz,
                                         float c2, float r2) {
    const float p2 = fadd(fadd(fmul(x, x), fmul(y, y)), fmul(z, z));
    const float cp = ffma(cz, z, ffma(cy, y, fmul(cx, x)));
    return fsub(fadd(c2, p2), fmul(2.0f, cp)) < r2;
}

__device__ __forceinline__ int cell_of(float x, float y, float z) {
    int ci = (int)(x * 10.0f); ci = ci < 0 ? 0 : (ci > 9 ? 9 : ci);
    int cj = (int)(y * 10.0f); cj = cj < 0 ? 0 : (cj > 9 ? 9 : cj);
    int ck = (int)(z * 10.0f); ck = ck < 0 ? 0 : (ck > 9 ? 9 : ck);
    return (ck * CELLS + cj) * CELLS + ci;   // x fastest
}

// ===========================================================================
// R12: FUSED COOPERATIVE KERNEL. 1024 blocks x 256 threads, all resident
// (launch_bounds(256,4): <=128 VGPR, LDS ~8.8KB -> 4 blocks/CU guaranteed).
// 3 grid.sync()s replace 3 dispatch boundaries. Phases:
//   A: transpose 1 tile (32 pts) per block -> pf; blocks 0/1 additionally
//      bin their whole batch (LDS hist + in-block scan -> starts/cursor).
//   C: scatter own 32 points (coords from LDS tile, no global reload).
//   D: ball query, 2 centers per wave (4096 waves x 2 = 8192).
//   E: gather, 1 (b,k,m) per thread (262144 threads = 16 waves/CU, 2x the
//      old gather's TLP for its latency-bound random record reads).
// Fallback to the proven 4-dispatch path if cooperative launch errors.
// ===========================================================================
struct PrepSh {
    float tile[32][37];
    int   hist[NCELL];
    int   wsum[4];
};
union FusedSh {
    PrepSh   p;
    unsigned bitmap[4][N_PTS / 32];   // 8 KB, used only after phase C
};

__global__ __launch_bounds__(256, 4) void fused_kernel(
    const float* __restrict__ points,    // (B,3,N)
    const float* __restrict__ centers,   // (B,3,M)
    const float* __restrict__ feats,     // (B,C,N)
    int* __restrict__ starts,            // (B,1001)
    int* __restrict__ cursor,            // (B,1000)
    float4* __restrict__ binned,         // (B,N)
    int* __restrict__ idx_out,           // (B,K,M)
    float* __restrict__ pf,              // (B,N,36)
    float* __restrict__ out)             // (B,35,K,M)
{
    cg::grid_group grid = cg::this_grid();
    __shared__ FusedSh sh;
    const int t    = threadIdx.x;
    const int lane = t & 63;
    const int wid  = t >> 6;
    const int blk  = blockIdx.x;

    // ---- phase A: transpose own 32-pt tile ------------------------------
    const int bt = blk >> 9;            // tile batch
    const int n0 = (blk & 511) * 32;    // tile origin
    {
        for (int i = t; i < NCH * 32; i += 256) {
            const int r = i >> 5;       // 0..34
            const int c = i & 31;
            float v;
            if (r < 3) v = points[(bt * 3 + r) * N_PTS + n0 + c];
            else       v = feats[(bt * C_FT + (r - 3)) * N_PTS + n0 + c];
            sh.p.tile[c][r] = v;
        }
        if (t < 32) sh.p.tile[t][35] = 0.0f;
        __syncthreads();
        float* __restrict__ dst = pf + ((size_t)bt * N_PTS + n0) * 36;
        for (int o = t; o < 32 * 36; o += 256) {
            const int c = o / 36;
            const int r = o - c * 36;
            dst[o] = sh.p.tile[c][r];
        }
        // tile rows 0..2 stay live in LDS until phase C (hist is disjoint)
    }

    // ---- phase A (blocks 0/1 only): bin whole batch + in-block scan -----
    if (blk < B_SZ) {
        const int b = blk;
        for (int c = t; c < NCELL; c += 256) sh.p.hist[c] = 0;
        __syncthreads();
        const float* __restrict__ px = points + (b * 3 + 0) * N_PTS;
        const float* __restrict__ py = points + (b * 3 + 1) * N_PTS;
        const float* __restrict__ pz = points + (b * 3 + 2) * N_PTS;
#pragma unroll 4
        for (int i = 0; i < 64; ++i) {
            const int n = t + i * 256;
            atomicAdd(&sh.p.hist[cell_of(px[n], py[n], pz[n])], 1);
        }
        __syncthreads();
        // scan 1000 cells, 4 per thread (threads 250..255 idle-but-present)
        const int c0 = 4 * t;
        int v0 = 0, v1 = 0, v2 = 0, v3 = 0;
        if (c0 < NCELL) {
            v0 = sh.p.hist[c0];     v1 = sh.p.hist[c0 + 1];
            v2 = sh.p.hist[c0 + 2]; v3 = sh.p.hist[c0 + 3];
        }
        const int s = v0 + v1 + v2 + v3;
        int incl = s;
        for (int off = 1; off < 64; off <<= 1) {
            const int u = __shfl_up(incl, off);
            if (lane >= off) incl += u;
        }
        if (lane == 63) sh.p.wsum[wid] = incl;
        __syncthreads();
        if (t == 0) {
            int acc = 0;
            for (int w2 = 0; w2 < 4; ++w2) {
                const int x = sh.p.wsum[w2]; sh.p.wsum[w2] = acc; acc += x;
            }
        }
        __syncthreads();
        if (c0 < NCELL) {
            int e = incl - s + sh.p.wsum[wid];
            starts[b * (NCELL + 1) + c0] = e;     cursor[b * NCELL + c0] = e;     e += v0;
            starts[b * (NCELL + 1) + c0 + 1] = e; cursor[b * NCELL + c0 + 1] = e; e += v1;
            starts[b * (NCELL + 1) + c0 + 2] = e; cursor[b * NCELL + c0 + 2] = e; e += v2;
            starts[b * (NCELL + 1) + c0 + 3] = e; cursor[b * NCELL + c0 + 3] = e; e += v3;
            if (c0 + 4 == NCELL) starts[b * (NCELL + 1) + NCELL] = e;
        }
    }

    grid.sync();   // s1: cursor/starts + pf tiles globally visible

    // ---- phase C: scatter own 32 points (coords from LDS tile) ----------
    if (t < 32) {
        const float x = sh.p.tile[t][0];
        const float y = sh.p.tile[t][1];
        const float z = sh.p.tile[t][2];
        const int pos = atomicAdd(&cursor[bt * NCELL + cell_of(x, y, z)], 1);
        binned[bt * N_PTS + pos] = make_float4(x, y, z, __int_as_float(n0 + t));
    }

    grid.sync();   // s2: binned complete

    // ---- phase D: ball query, 2 centers per wave ------------------------
    const float r2 = (float)(0.1 * 0.1);
    for (int cc = 0; cc < 2; ++cc) {
        const int gw = blk * 4 + wid + cc * 4096;   // 0..8191
        const int b = gw >> 12;
        const int m = gw & (M_CTR - 1);

        const float cx = centers[(b * 3 + 0) * M_CTR + m];
        const float cy = centers[(b * 3 + 1) * M_CTR + m];
        const float cz = centers[(b * 3 + 2) * M_CTR + m];
        const float c2 = fadd(fadd(fmul(cx, cx), fmul(cy, cy)), fmul(cz, cz));

        unsigned* bm = sh.bitmap[wid];
#pragma unroll
        for (int j = 0; j < 8; ++j) bm[j * 64 + lane] = 0u;   // conflict-free

        int ci = (int)(cx * 10.0f); ci = ci < 0 ? 0 : (ci > 9 ? 9 : ci);
        int cj = (int)(cy * 10.0f); cj = cj < 0 ? 0 : (cj > 9 ? 9 : cj);
        int ck = (int)(cz * 10.0f); ck = ck < 0 ? 0 : (ck > 9 ? 9 : ck);
        ci = __builtin_amdgcn_readfirstlane(ci);
        cj = __builtin_amdgcn_readfirstlane(cj);
        ck = __builtin_amdgcn_readfirstlane(ck);
        const int i0 = ci > 0 ? ci - 1 : 0;
        const int i1 = ci < 9 ? ci + 1 : 9;
        const int* st = starts + b * (NCELL + 1);
        const float4* __restrict__ bp = binned + b * N_PTS;

        int lo_d[9], hi_d[9];
#pragma unroll
        for (int d = 0; d < 9; ++d) {
            const int jj = cj + (d % 3) - 1;
            const int kk = ck + (d / 3) - 1;
            const bool ok = (jj >= 0) & (jj <= 9) & (kk >= 0) & (kk <= 9);
            const int base = ok ? (kk * CELLS + jj) * CELLS : 0;
            const int lo = st[base + i0];
            const int hi = st[base + i1 + 1];
            lo_d[d] = ok ? lo : 0;
            hi_d[d] = ok ? hi : 0;
        }

#pragma unroll
        for (int d = 0; d < 9; ++d) {
            const int lo = lo_d[d];
            const int hi = hi_d[d];
            for (int s0 = lo; s0 < hi; s0 += 64) {
                const int tt = s0 + lane;
                if (tt < hi) {
                    const float4 p = bp[tt];
                    if (bq_valid(p.x, p.y, p.z, cx, cy, cz, c2, r2)) {
                        const int n = __float_as_int(p.w);
                        atomicOr((int*)&bm[(((n >> 5) & 7) << 6) + (n >> 8)],
                                 1 << (n & 31));
                    }
                }
            }
        }

        unsigned w[8];
        int cnt = 0;
#pragma unroll
        for (int j = 0; j < 8; ++j) {
            w[j] = bm[j * 64 + lane];
            cnt += __popc(w[j]);
        }

        int incl = cnt;
        for (int off = 1; off < 64; off <<= 1) {
            const int v = __shfl_up(incl, off);
            if (lane >= off) incl += v;
        }
        const int total = __shfl(incl, 63);
        int slot = incl - cnt;

        int firstbit = 0x7fffffff;
#pragma unroll
        for (int j = 0; j < 8; ++j) {
            if (w[j] && firstbit == 0x7fffffff)
                firstbit = lane * 256 + j * 32 + (__ffs(w[j]) - 1);
        }
        for (int off = 32; off > 0; off >>= 1)
            firstbit = min(firstbit, __shfl_xor(firstbit, off));
        const int first_idx = (total == 0) ? 0 : firstbit;

        int* __restrict__ dst = idx_out + (b * K_NB) * M_CTR + m;
#pragma unroll
        for (int j = 0; j < 8; ++j) {
            unsigned x = w[j];
            while (x && slot < K_NB) {
                const int bit = __ffs(x) - 1;
                dst[slot * M_CTR] = lane * 256 + j * 32 + bit;
                x &= x - 1;
                ++slot;
            }
        }
        if (lane >= total && lane < K_NB) dst[lane * M_CTR] = first_idx;
    }

    grid.sync();   // s3: idx complete

    // ---- phase E: gather, 1 (b,k,m) per thread --------------------------
    {
        const int tg = blk * 256 + t;            // 0..262143
        const int m = tg & (M_CTR - 1);
        const int k = (tg >> 12) & (K_NB - 1);
        const int b = tg >> 17;

        const int n = idx_out[(b * K_NB + k) * M_CTR + m];
        const float4* __restrict__ src =
            (const float4*)(pf + ((size_t)b * N_PTS + n) * 36);
        float4 f[9];
#pragma unroll
        for (int i = 0; i < 9; ++i) f[i] = src[i];

        f[0].x -= centers[(b * 3 + 0) * M_CTR + m];   // single f32 subtract
        f[0].y -= centers[(b * 3 + 1) * M_CTR + m];
        f[0].z -= centers[(b * 3 + 2) * M_CTR + m];

        float* __restrict__ o =
            out + ((size_t)(b * NCH) * K_NB + k) * M_CTR + m;
#pragma unroll
        for (int i = 0; i < 9; ++i) {
#pragma unroll
            for (int j = 0; j < 4; ++j) {
                const int ch = 4 * i + j;
                if (ch < NCH) {
                    const float v = (j == 0) ? f[i].x : (j == 1) ? f[i].y
                                  : (j == 2) ? f[i].z : f[i].w;
                    __builtin_nontemporal_store(v, &o[(size_t)ch * CH_STRIDE]);
                }
            }
        }
    }
}

// ===========================================================================
// FALLBACK: proven 4-dispatch path (R11/R2, 104.3 us) — used only if the
// cooperative launch is rejected (occupancy / capture support).
// ===========================================================================
__global__ __launch_bounds__(1024) void prep_kernel(
    const float* __restrict__ points, const float* __restrict__ feats,
    int* __restrict__ starts, int* __restrict__ cursor,
    float* __restrict__ pf)
{
    if (blockIdx.x < B_SZ) {
        const int b = blockIdx.x;
        const int t = threadIdx.x;
        const int lane = t & 63, wid = t >> 6;
        __shared__ int h[NCELL];
        __shared__ int wsum[16];
        for (int c = t; c < NCELL; c += 1024) h[c] = 0;
        __syncthreads();
        const float* __restrict__ px = points + (b * 3 + 0) * N_PTS;
        const float* __restrict__ py = points + (b * 3 + 1) * N_PTS;
        const float* __restrict__ pz = points + (b * 3 + 2) * N_PTS;
#pragma unroll
        for (int i = 0; i < 16; ++i) {
            const int n = t + i * 1024;
            atomicAdd(&h[cell_of(px[n], py[n], pz[n])], 1);
        }
        __syncthreads();
        const int v = (t < NCELL) ? h[t] : 0;
        int incl = v;
        for (int off = 1; off < 64; off <<= 1) {
            const int u = __shfl_up(incl, off);
            if (lane >= off) incl += u;
        }
        if (lane == 63) wsum[wid] = incl;
        __syncthreads();
        if (wid == 0 && lane < 16) {
            const int s = wsum[lane];
            int in2 = s;
            for (int off = 1; off < 16; off <<= 1) {
                const int u = __shfl_up(in2, off);
                if (lane >= off) in2 += u;
            }
            wsum[lane] = in2 - s;
        }
        __syncthreads();
        if (t < NCELL) {
            const int excl = incl - v + wsum[wid];
            starts[b * (NCELL + 1) + t] = excl;
            cursor[b * NCELL + t] = excl;
            if (t == NCELL - 1) starts[b * (NCELL + 1) + NCELL] = excl + v;
        }
    } else {
        __shared__ float tile[64][37];
        const int bid = blockIdx.x - B_SZ;
        const int t  = threadIdx.x;
        const int b  = bid >> 8;
        const int n0 = (bid & 255) * 64;
        for (int i = t; i < NCH * 64; i += 1024) {
            const int r = i >> 6;
            const int c = i & 63;
            float v;
            if (r < 3) v = points[(b * 3 + r) * N_PTS + n0 + c];
            else       v = feats[(b * C_FT + (r - 3)) * N_PTS + n0 + c];
            tile[c][r] = v;
        }
        if (t < 64) tile[t][35] = 0.0f;
        __syncthreads();
        float* __restrict__ dst = pf + ((size_t)b * N_PTS + n0) * 36;
        for (int o = t; o < 64 * 36; o += 1024) {
            const int c = o / 36;
            const int r = o - c * 36;
            dst[o] = tile[c][r];
        }
    }
}

__global__ __launch_bounds__(256) void scatter_kernel(
    const float* __restrict__ points, int* __restrict__ cursor,
    float4* __restrict__ binned) {
    const int t = blockIdx.x * 256 + threadIdx.x;
    const int b = t >> 14, n = t & (N_PTS - 1);
    const float x = points[(b * 3 + 0) * N_PTS + n];
    const float y = points[(b * 3 + 1) * N_PTS + n];
    const float z = points[(b * 3 + 2) * N_PTS + n];
    const int pos = atomicAdd(&cursor[b * NCELL + cell_of(x, y, z)], 1);
    binned[b * N_PTS + pos] = make_float4(x, y, z, __int_as_float(n));
}

__global__ __launch_bounds__(256) void ball_query_kernel(
    const float4* __restrict__ binned, const float* __restrict__ centers,
    const int* __restrict__ starts, int* __restrict__ idx_out)
{
    const int lane = threadIdx.x & 63;
    const int wid  = threadIdx.x >> 6;
    const int cid  = blockIdx.x * 4 + wid;
    const int b = cid >> 12;
    const int m = cid & (M_CTR - 1);
    const float r2 = (float)(0.1 * 0.1);
    const float cx = centers[(b * 3 + 0) * M_CTR + m];
    const float cy = centers[(b * 3 + 1) * M_CTR + m];
    const float cz = centers[(b * 3 + 2) * M_CTR + m];
    const float c2 = fadd(fadd(fmul(cx, cx), fmul(cy, cy)), fmul(cz, cz));
    __shared__ unsigned bitmap[4][N_PTS / 32];
    unsigned* bm = bitmap[wid];
#pragma unroll
    for (int j = 0; j < 8; ++j) bm[j * 64 + lane] = 0u;
    int ci = (int)(cx * 10.0f); ci = ci < 0 ? 0 : (ci > 9 ? 9 : ci);
    int cj = (int)(cy * 10.0f); cj = cj < 0 ? 0 : (cj > 9 ? 9 : cj);
    int ck = (int)(cz * 10.0f); ck = ck < 0 ? 0 : (ck > 9 ? 9 : ck);
    ci = __builtin_amdgcn_readfirstlane(ci);
    cj = __builtin_amdgcn_readfirstlane(cj);
    ck = __builtin_amdgcn_readfirstlane(ck);
    const int i0 = ci > 0 ? ci - 1 : 0;
    const int i1 = ci < 9 ? ci + 1 : 9;
    const int* st = starts + b * (NCELL + 1);
    const float4* __restrict__ bp = binned + b * N_PTS;
    int lo_d[9], hi_d[9];
#pragma unroll
    for (int d = 0; d < 9; ++d) {
        const int jj = cj + (d % 3) - 1;
        const int kk = ck + (d / 3) - 1;
        const bool ok = (jj >= 0) & (jj <= 9) & (kk >= 0) & (kk <= 9);
        const int base = ok ? (kk * CELLS + jj) * CELLS : 0;
        const int lo = st[base + i0];
        const int hi = st[base + i1 + 1];
        lo_d[d] = ok ? lo : 0;
        hi_d[d] = ok ? hi : 0;
    }
#pragma unroll
    for (int d = 0; d < 9; ++d) {
        const int lo = lo_d[d];
        const int hi = hi_d[d];
        for (int s0 = lo; s0 < hi; s0 += 64) {
            const int t = s0 + lane;
            if (t < hi) {
                const float4 p = bp[t];
                if (bq_valid(p.x, p.y, p.z, cx, cy, cz, c2, r2)) {
                    const int n = __float_as_int(p.w);
                    atomicOr((int*)&bm[(((n >> 5) & 7) << 6) + (n >> 8)],
                             1 << (n & 31));
                }
            }
        }
    }
    unsigned w[8];
    int cnt = 0;
#pragma unroll
    for (int j = 0; j < 8; ++j) { w[j] = bm[j * 64 + lane]; cnt += __popc(w[j]); }
    int incl = cnt;
    for (int off = 1; off < 64; off <<= 1) {
        const int v = __shfl_up(incl, off);
        if (lane >= off) incl += v;
    }
    const int total = __shfl(incl, 63);
    int slot = incl - cnt;
    int firstbit = 0x7fffffff;
#pragma unroll
    for (int j = 0; j < 8; ++j) {
        if (w[j] && firstbit == 0x7fffffff)
            firstbit = lane * 256 + j * 32 + (__ffs(w[j]) - 1);
    }
    for (int off = 32; off > 0; off >>= 1)
        firstbit = min(firstbit, __shfl_xor(firstbit, off));
    const int first_idx = (total == 0) ? 0 : firstbit;
    int* __restrict__ dst = idx_out + (b * K_NB) * M_CTR + m;
#pragma unroll
    for (int j = 0; j < 8; ++j) {
        unsigned x = w[j];
        while (x && slot < K_NB) {
            const int bit = __ffs(x) - 1;
            dst[slot * M_CTR] = lane * 256 + j * 32 + bit;
            x &= x - 1;
            ++slot;
        }
    }
    if (lane >= total && lane < K_NB) dst[lane * M_CTR] = first_idx;
}

__global__ __launch_bounds__(256) void gather_kernel(
    const float* __restrict__ pf, const float* __restrict__ centers,
    const int* __restrict__ idx, float* __restrict__ out)
{
    const int t = blockIdx.x * 256 + threadIdx.x;
    const int m = (t & (M_CTR / 2 - 1)) * 2;
    const int k = (t >> 11) & (K_NB - 1);
    const int b = t >> 16;
    const int2 nn = *(const int2*)&idx[(b * K_NB + k) * M_CTR + m];
    const float4* __restrict__ s0 =
        (const float4*)(pf + ((size_t)b * N_PTS + nn.x) * 36);
    const float4* __restrict__ s1 =
        (const float4*)(pf + ((size_t)b * N_PTS + nn.y) * 36);
    float4 f0[9], f1[9];
#pragma unroll
    for (int i = 0; i < 9; ++i) { f0[i] = s0[i]; f1[i] = s1[i]; }
    const float2 cx = *(const float2*)&centers[(b * 3 + 0) * M_CTR + m];
    const float2 cy = *(const float2*)&centers[(b * 3 + 1) * M_CTR + m];
    const float2 cz = *(const float2*)&centers[(b * 3 + 2) * M_CTR + m];
    float v0[36], v1[36];
#pragma unroll
    for (int i = 0; i < 9; ++i) {
        v0[4 * i + 0] = f0[i].x; v0[4 * i + 1] = f0[i].y;
        v0[4 * i + 2] = f0[i].z; v0[4 * i + 3] = f0[i].w;
        v1[4 * i + 0] = f1[i].x; v1[4 * i + 1] = f1[i].y;
        v1[4 * i + 2] = f1[i].z; v1[4 * i + 3] = f1[i].w;
    }
    v0[0] -= cx.x; v0[1] -= cy.x; v0[2] -= cz.x;
    v1[0] -= cx.y; v1[1] -= cy.y; v1[2] -= cz.y;
    float* __restrict__ o = out + ((size_t)b * NCH * K_NB + k) * M_CTR + m;
#pragma unroll
    for (int ch = 0; ch < NCH; ++ch) {
        vfloat2 pv; pv.x = v0[ch]; pv.y = v1[ch];
        __builtin_nontemporal_store(pv, (vfloat2*)&o[(size_t)ch * CH_STRIDE]);
    }
}

extern "C" void kernel_launch(void* const* d_in, const int* in_sizes, int n_in,
                              void* d_out, int out_size, void* d_ws, size_t ws_size,
                              hipStream_t stream) {
    const float* points  = (const float*)d_in[0];
    const float* centers = (const float*)d_in[1];
    const float* feats   = (const float*)d_in[2];
    float* out = (float*)d_out;

    char* ws = (char*)d_ws;
    int*    idxp   = (int*)ws;                               // 1 MiB
    float*  pf     = (float*)(ws + (1u << 20));              // 4.5 MiB
    int*    cursor = (int*)(ws + 5716 * 1024);               // 8 KB
    int*    starts = (int*)(ws + 5732 * 1024);               // 8 KB
    float4* binned = (float4*)(ws + 5764 * 1024);            // 512 KB

    void* kargs[] = { (void*)&points, (void*)&centers, (void*)&feats,
                      (void*)&starts, (void*)&cursor, (void*)&binned,
                      (void*)&idxp,   (void*)&pf,     (void*)&out };
    hipError_t err = hipLaunchCooperativeKernel(
        fused_kernel, dim3(1024), dim3(256), kargs, 0u, stream);
    if (err != hipSuccess) {
        (void)hipGetLastError();   // clear error state; fall back
        prep_kernel<<<B_SZ + B_SZ * (N_PTS / 64), 1024, 0, stream>>>(
            points, feats, starts, cursor, pf);
        scatter_kernel<<<(B_SZ * N_PTS) / 256, 256, 0, stream>>>(
            points, cursor, binned);
        ball_query_kernel<<<(B_SZ * M_CTR) / 4, 256, 0, stream>>>(
            binned, centers, starts, idxp);
        gather_kernel<<<(B_SZ * K_NB * M_CTR / 2) / 256, 256, 0, stream>>>(
            pf, centers, idxp, out);
    }
}

// Round 4
// 114.332 us; speedup vs baseline: 4.2108x; 4.2108x over previous
//
#include <hip/hip_runtime.h>

#define B_SZ  2
#define N_PTS 16384
#define M_CTR 4096
#define C_FT  32
#define K_NB  32
#define NCH   35   // 3 + C_FT
#define CH_STRIDE (K_NB * M_CTR)   // 131072
#define CELLS 10
#define NCELL (CELLS * CELLS * CELLS)

typedef float vfloat2 __attribute__((ext_vector_type(2)));  // NT-store-able

// ---------------------------------------------------------------------------
// Exact single-rounded f32 ops, opaque to the compiler. v_fma_f32 ONLY where
// the numpy golden fuses (einsum cp accumulation). absmax==0.0 since R6 —
// DO NOT change the math.
// ---------------------------------------------------------------------------
__device__ __forceinline__ float fmul(float a, float b) {
    float r; asm("v_mul_f32 %0, %1, %2" : "=v"(r) : "v"(a), "v"(b)); return r;
}
__device__ __forceinline__ float fadd(float a, float b) {
    float r; asm("v_add_f32 %0, %1, %2" : "=v"(r) : "v"(a), "v"(b)); return r;
}
__device__ __forceinline__ float fsub(float a, float b) {
    float r; asm("v_sub_f32 %0, %1, %2" : "=v"(r) : "v"(a), "v"(b)); return r;
}
__device__ __forceinline__ float ffma(float a, float b, float c) {
    float r; asm("v_fma_f32 %0, %1, %2, %3" : "=v"(r) : "v"(a), "v"(b), "v"(c));
    return r;
}

__device__ __forceinline__ bool bq_valid(float x, float y, float z,
                                         float cx, float cy, float cz,
                                         float c2, float r2) {
    const float p2 = fadd(fadd(fmul(x, x), fmul(y, y)), fmul(z, z));
    const float cp = ffma(cz, z, ffma(cy, y, fmul(cx, x)));
    return fsub(fadd(c2, p2), fmul(2.0f, cp)) < r2;
}

__device__ __forceinline__ int cell_of(float x, float y, float z) {
    int ci = (int)(x * 10.0f); ci = ci < 0 ? 0 : (ci > 9 ? 9 : ci);
    int cj = (int)(y * 10.0f); cj = cj < 0 ? 0 : (cj > 9 ? 9 : cj);
    int ck = (int)(z * 10.0f); ck = ck < 0 ? 0 : (ck > 9 ? 9 : ck);
    return (ck * CELLS + cj) * CELLS + ci;   // x fastest
}

// ---------------------------------------------------------------------------
// Prep, ONE dispatch @1024 threads. R13: scatter FOLDED into the bin blocks.
//   blocks 0..1   : per-batch LDS hist (16 pts/thread) -> in-block
//                   shuffle-scan -> starts (global) ; then the SAME block
//                   scatters its 16384 points via LDS-cursor atomics
//                   (hist array reused as cursor). Intra-cell order is
//                   irrelevant: bq's N-bitmap restores global index order.
//                   Kills the scatter dispatch + gap + global cursor.
//   blocks 2..513 : transpose points+feats -> pf (B,N,36)  (runs parallel).
// ---------------------------------------------------------------------------
__global__ __launch_bounds__(1024) void prep_kernel(
    const float* __restrict__ points,   // (B,3,N)
    const float* __restrict__ feats,    // (B,C,N)
    int* __restrict__ starts,           // (B,1001)
    float4* __restrict__ binned,        // (B,N) {x,y,z,idx}
    float* __restrict__ pf)             // (B,N,36)
{
    if (blockIdx.x < B_SZ) {
        const int b = blockIdx.x;
        const int t = threadIdx.x;      // 0..1023
        const int lane = t & 63, wid = t >> 6;
        __shared__ int h[NCELL];        // hist -> (after scan) cursor
        __shared__ int wsum[16];
        for (int c = t; c < NCELL; c += 1024) h[c] = 0;
        __syncthreads();

        const float* __restrict__ px = points + (b * 3 + 0) * N_PTS;
        const float* __restrict__ py = points + (b * 3 + 1) * N_PTS;
        const float* __restrict__ pz = points + (b * 3 + 2) * N_PTS;
        int cells[16];
#pragma unroll
        for (int i = 0; i < 16; ++i) {
            const int n = t + i * 1024;
            cells[i] = cell_of(px[n], py[n], pz[n]);
            atomicAdd(&h[cells[i]], 1);
        }
        __syncthreads();

        const int v = (t < NCELL) ? h[t] : 0;
        int incl = v;
        for (int off = 1; off < 64; off <<= 1) {
            const int u = __shfl_up(incl, off);
            if (lane >= off) incl += u;
        }
        if (lane == 63) wsum[wid] = incl;
        __syncthreads();
        if (wid == 0 && lane < 16) {
            const int s = wsum[lane];
            int in2 = s;
            for (int off = 1; off < 16; off <<= 1) {
                const int u = __shfl_up(in2, off);
                if (lane >= off) in2 += u;
            }
            wsum[lane] = in2 - s;       // exclusive wave offset
        }
        __syncthreads();
        if (t < NCELL) {
            const int excl = incl - v + wsum[wid];
            starts[b * (NCELL + 1) + t] = excl;
            h[t] = excl;                // LDS cursor
            if (t == NCELL - 1) starts[b * (NCELL + 1) + NCELL] = excl + v;
        }
        __syncthreads();

        // scatter pass: coords reload is L2-warm; cells kept in regs
        float4* __restrict__ bb = binned + b * N_PTS;
#pragma unroll
        for (int i = 0; i < 16; ++i) {
            const int n = t + i * 1024;
            const float x = px[n], y = py[n], z = pz[n];
            const int pos = atomicAdd(&h[cells[i]], 1);
            bb[pos] = make_float4(x, y, z, __int_as_float(n));
        }
    } else {
        __shared__ float tile[64][37];
        const int bid = blockIdx.x - B_SZ;
        const int t  = threadIdx.x;
        const int b  = bid >> 8;
        const int n0 = (bid & 255) * 64;
        for (int i = t; i < NCH * 64; i += 1024) {
            const int r = i >> 6;
            const int c = i & 63;
            float v;
            if (r < 3) v = points[(b * 3 + r) * N_PTS + n0 + c];
            else       v = feats[(b * C_FT + (r - 3)) * N_PTS + n0 + c];
            tile[c][r] = v;
        }
        if (t < 64) tile[t][35] = 0.0f;
        __syncthreads();
        float* __restrict__ dst = pf + ((size_t)b * N_PTS + n0) * 36;
        for (int o = t; o < 64 * 36; o += 1024) {
            const int c = o / 36;
            const int r = o - c * 36;
            dst[o] = tile[c][r];
        }
    }
}

// ---------------------------------------------------------------------------
// Ball query, binned. One wave per center; 27-cell neighborhood (~440
// candidates). Per-wave LDS bitmap over N restores exact index order.
// R13: XCD-aware batch split — XCDs 0-3 serve batch 0, XCDs 4-7 batch 1
// (blk&7 = XCD on MI355X round-robin dispatch). Per-XCD L2 working set
// (binned 256KB + centers 48KB per batch) stays clean per XCD.
// ---------------------------------------------------------------------------
__global__ __launch_bounds__(256) void ball_query_kernel(
    const float4* __restrict__ binned,   // (B,N) {x,y,z,idx}
    const float* __restrict__ centers,   // (B,3,M)
    const int* __restrict__ starts,      // (B,1001)
    int* __restrict__ idx_out)           // (B,K,M)
{
    const int lane = threadIdx.x & 63;
    const int wid  = threadIdx.x >> 6;
    const int xcd  = blockIdx.x & 7;
    const int b    = xcd >> 2;                               // batch per XCD-half
    const int u    = (blockIdx.x >> 3) * 4 + (xcd & 3);      // 0..1023
    const int m    = u * 4 + wid;                            // 0..4095

    const float r2 = (float)(0.1 * 0.1);

    const float cx = centers[(b * 3 + 0) * M_CTR + m];
    const float cy = centers[(b * 3 + 1) * M_CTR + m];
    const float cz = centers[(b * 3 + 2) * M_CTR + m];
    const float c2 = fadd(fadd(fmul(cx, cx), fmul(cy, cy)), fmul(cz, cz));

    __shared__ unsigned bitmap[4][N_PTS / 32];   // 2 KB per wave
    unsigned* bm = bitmap[wid];
#pragma unroll
    for (int j = 0; j < 8; ++j) bm[j * 64 + lane] = 0u;   // conflict-free

    int ci = (int)(cx * 10.0f); ci = ci < 0 ? 0 : (ci > 9 ? 9 : ci);
    int cj = (int)(cy * 10.0f); cj = cj < 0 ? 0 : (cj > 9 ? 9 : cj);
    int ck = (int)(cz * 10.0f); ck = ck < 0 ? 0 : (ck > 9 ? 9 : ck);
    // wave-uniform by construction (one center per wave) -> tell the compiler
    ci = __builtin_amdgcn_readfirstlane(ci);
    cj = __builtin_amdgcn_readfirstlane(cj);
    ck = __builtin_amdgcn_readfirstlane(ck);
    const int i0 = ci > 0 ? ci - 1 : 0;
    const int i1 = ci < 9 ? ci + 1 : 9;
    const int* st = starts + b * (NCELL + 1);
    const float4* __restrict__ bp = binned + b * N_PTS;

    // Hoist all 9 strips' bounds: scalar address -> s_load, all in flight.
    int lo_d[9], hi_d[9];
#pragma unroll
    for (int d = 0; d < 9; ++d) {
        const int jj = cj + (d % 3) - 1;
        const int kk = ck + (d / 3) - 1;
        const bool ok = (jj >= 0) & (jj <= 9) & (kk >= 0) & (kk <= 9);
        const int base = ok ? (kk * CELLS + jj) * CELLS : 0;  // clamp: safe load
        const int lo = st[base + i0];
        const int hi = st[base + i1 + 1];
        lo_d[d] = ok ? lo : 0;
        hi_d[d] = ok ? hi : 0;
    }

#pragma unroll
    for (int d = 0; d < 9; ++d) {
        const int lo = lo_d[d];
        const int hi = hi_d[d];
        for (int s0 = lo; s0 < hi; s0 += 64) {
            const int t = s0 + lane;
            if (t < hi) {
                const float4 p = bp[t];
                if (bq_valid(p.x, p.y, p.z, cx, cy, cz, c2, r2)) {
                    const int n = __float_as_int(p.w);
                    // word w = n>>5 lives at slot (w&7)*64 + (w>>3)
                    atomicOr((int*)&bm[(((n >> 5) & 7) << 6) + (n >> 8)],
                             1 << (n & 31));
                }
            }
        }
    }

    unsigned w[8];
    int cnt = 0;
#pragma unroll
    for (int j = 0; j < 8; ++j) {            // slot j*64+lane == word lane*8+j
        w[j] = bm[j * 64 + lane];
        cnt += __popc(w[j]);
    }

    int incl = cnt;
    for (int off = 1; off < 64; off <<= 1) {
        const int v = __shfl_up(incl, off);
        if (lane >= off) incl += v;
    }
    const int total = __shfl(incl, 63);
    int slot = incl - cnt;

    int firstbit = 0x7fffffff;
#pragma unroll
    for (int j = 0; j < 8; ++j) {
        if (w[j] && firstbit == 0x7fffffff)
            firstbit = lane * 256 + j * 32 + (__ffs(w[j]) - 1);
    }
    for (int off = 32; off > 0; off >>= 1)
        firstbit = min(firstbit, __shfl_xor(firstbit, off));
    const int first_idx = (total == 0) ? 0 : firstbit;

    int* __restrict__ dst = idx_out + (b * K_NB) * M_CTR + m;
#pragma unroll
    for (int j = 0; j < 8; ++j) {
        unsigned x = w[j];
        while (x && slot < K_NB) {
            const int bit = __ffs(x) - 1;
            dst[slot * M_CTR] = lane * 256 + j * 32 + bit;
            x &= x - 1;
            ++slot;
        }
    }
    if (lane >= total && lane < K_NB) dst[lane * M_CTR] = first_idx;
}

// ---------------------------------------------------------------------------
// Gather: R9's 2-wide form (best measured) + R13 XCD-aware batch split:
// pf is 4.72 MB total but 2.36 MB/batch — splitting batches across XCD
// halves keeps each XCD's gather working set inside its 4 MiB L2 (before,
// every XCD touched both batches = 4.72 MB + idx/centers -> marginal
// thrash). NT stores keep the 36.7 MB output stream out of L2.
// ---------------------------------------------------------------------------
__global__ __launch_bounds__(256) void gather_kernel(
    const float* __restrict__ pf,       // (B,N,36)
    const float* __restrict__ centers,  // (B,3,M)
    const int* __restrict__ idx,        // (B,K,M)
    float* __restrict__ out)            // (B,35,K,M)
{
    const int xcd = blockIdx.x & 7;
    const int b   = xcd >> 2;                               // batch per XCD-half
    const int u   = (blockIdx.x >> 3) * 4 + (xcd & 3);      // 0..255
    const int g   = u * 256 + threadIdx.x;                  // 0..65535
    const int m = (g & (M_CTR / 2 - 1)) * 2;
    const int k = g >> 11;                                  // 0..31

    const int2 nn = *(const int2*)&idx[(b * K_NB + k) * M_CTR + m];
    const float4* __restrict__ s0 =
        (const float4*)(pf + ((size_t)b * N_PTS + nn.x) * 36);
    const float4* __restrict__ s1 =
        (const float4*)(pf + ((size_t)b * N_PTS + nn.y) * 36);

    float4 f0[9], f1[9];
#pragma unroll
    for (int i = 0; i < 9; ++i) { f0[i] = s0[i]; f1[i] = s1[i]; }

    const float2 cx = *(const float2*)&centers[(b * 3 + 0) * M_CTR + m];
    const float2 cy = *(const float2*)&centers[(b * 3 + 1) * M_CTR + m];
    const float2 cz = *(const float2*)&centers[(b * 3 + 2) * M_CTR + m];

    float v0[36], v1[36];
#pragma unroll
    for (int i = 0; i < 9; ++i) {
        v0[4 * i + 0] = f0[i].x; v0[4 * i + 1] = f0[i].y;
        v0[4 * i + 2] = f0[i].z; v0[4 * i + 3] = f0[i].w;
        v1[4 * i + 0] = f1[i].x; v1[4 * i + 1] = f1[i].y;
        v1[4 * i + 2] = f1[i].z; v1[4 * i + 3] = f1[i].w;
    }
    v0[0] -= cx.x; v0[1] -= cy.x; v0[2] -= cz.x;   // single f32 subtract
    v1[0] -= cx.y; v1[1] -= cy.y; v1[2] -= cz.y;

    float* __restrict__ o = out + ((size_t)b * NCH * K_NB + k) * M_CTR + m;
#pragma unroll
    for (int ch = 0; ch < NCH; ++ch) {
        vfloat2 pv; pv.x = v0[ch]; pv.y = v1[ch];
        __builtin_nontemporal_store(pv, (vfloat2*)&o[(size_t)ch * CH_STRIDE]);
    }
}

extern "C" void kernel_launch(void* const* d_in, const int* in_sizes, int n_in,
                              void* d_out, int out_size, void* d_ws, size_t ws_size,
                              hipStream_t stream) {
    const float* points  = (const float*)d_in[0];
    const float* centers = (const float*)d_in[1];
    const float* feats   = (const float*)d_in[2];
    float* out = (float*)d_out;

    char* ws = (char*)d_ws;
    int*    idx    = (int*)ws;                               // 1 MiB
    float*  pf     = (float*)(ws + (1u << 20));              // 4.5 MiB
    int*    starts = (int*)(ws + 5732 * 1024);               // 8 KB
    float4* binned = (float4*)(ws + 5764 * 1024);            // 512 KB

    prep_kernel<<<B_SZ + B_SZ * (N_PTS / 64), 1024, 0, stream>>>(
        points, feats, starts, binned, pf);
    ball_query_kernel<<<(B_SZ * M_CTR) / 4, 256, 0, stream>>>(
        binned, centers, starts, idx);
    gather_kernel<<<(B_SZ * K_NB * M_CTR / 2) / 256, 256, 0, stream>>>(
        pf, centers, idx, out);
}